// Round 18
// baseline (64.933 us; speedup 1.0000x reference)
//
#include <hip/hip_runtime.h>
#include <stdint.h>

typedef _Float16 half8 __attribute__((ext_vector_type(8)));
typedef _Float16 half4 __attribute__((ext_vector_type(4)));
typedef __fp16 fp16x2 __attribute__((ext_vector_type(2)));
typedef float f32x4 __attribute__((ext_vector_type(4)));
typedef float float4v __attribute__((ext_vector_type(4)));
typedef float float2v __attribute__((ext_vector_type(2)));

#define S_LEN 2048
#define D_DIM 64
#define QBLK 128             // 2 q-groups of 16 rows per wave, 4 waves
#define KVBLK 64
#define NT (S_LEN / KVBLK)   // 32 kv tiles
#define NBH 32               // b*h
#define QSCALE 0.18033688f   // 0.125 * log2(e): softmax in base-2 domain
#define KSTR 72              // fallback-kernel K stride

#if __has_builtin(__builtin_amdgcn_exp2f)
#define EXP2(x) __builtin_amdgcn_exp2f(x)
#else
#define EXP2(x) exp2f(x)
#endif
#define MAX3(a, b, c) fmaxf(fmaxf((a), (b)), (c))

static __device__ __forceinline__ void glds16(const void* g, void* l) {
  __builtin_amdgcn_global_load_lds(
      (__attribute__((address_space(1))) void*)(g),
      (__attribute__((address_space(3))) void*)(l), 16, 0, 0);
}
#define SBAR() do { asm volatile("" ::: "memory"); __builtin_amdgcn_s_barrier(); asm volatile("" ::: "memory"); } while (0)

// ---------------- pre-pass: fp32 Q,K,V -> fp16 images in ws ----------------
// K image (per bh,tile 8KB): byte 128*r + 16*s holds K[64t+r][8*(s^(r&7))..+8]
// V image: tr-read subtiled (see fa_fwd2)
// Q image: row-major fp16, pre-scaled by QSCALE
__global__ __launch_bounds__(256)
void cvt_pack(const float* __restrict__ Kg, const float* __restrict__ Vg,
              const float* __restrict__ Qg, _Float16* __restrict__ Kw,
              _Float16* __restrict__ Vw, _Float16* __restrict__ Qw) {
  const int id = (int)(blockIdx.x * 256 + threadIdx.x);   // 0 .. 3*2^19-1
  const int tensor = id >> 19;
  const int cid = id & 0x7FFFF;
  if (tensor == 2) {   // Q: linear pack + scale
    const float* src = Qg + (size_t)cid * 8;
    float4v x = *(const float4v*)src;
    float4v y = *(const float4v*)(src + 4);
    half8 h = { (_Float16)(x[0] * QSCALE), (_Float16)(x[1] * QSCALE),
                (_Float16)(x[2] * QSCALE), (_Float16)(x[3] * QSCALE),
                (_Float16)(y[0] * QSCALE), (_Float16)(y[1] * QSCALE),
                (_Float16)(y[2] * QSCALE), (_Float16)(y[3] * QSCALE) };
    *(half8*)(Qw + (size_t)cid * 8) = h;
    return;
  }
  const int bht = cid >> 9;       // bh*NT + t
  const int bh = bht >> 5, t = bht & 31;
  const int loc = cid & 511;
  const int a = loc >> 3;
  const int s = loc & 7;
  size_t srcoff;
  if (tensor == 0) {
    const int r = a;
    srcoff = (size_t)bh * (S_LEN * D_DIM) + (size_t)(t * 64 + r) * D_DIM + 8 * (s ^ (r & 7));
  } else {
    const int TI = a, c2 = s;
    const int it = TI & 3;
    const int vgi = ((TI >> 3) & 3) | (((TI >> 2) & 1) << 2) | (((TI >> 5) & 1) << 3);
    const int kq = c2 >> 1, d8 = (c2 & 1) * 8;
    srcoff = (size_t)bh * (S_LEN * D_DIM) + (size_t)(t * 64 + 4 * vgi + kq) * D_DIM + it * 16 + d8;
  }
  const float* src = (tensor ? Vg : Kg) + srcoff;
  float4v x = *(const float4v*)src;
  float4v y = *(const float4v*)(src + 4);
  half8 h = { (_Float16)x[0], (_Float16)x[1], (_Float16)x[2], (_Float16)x[3],
              (_Float16)y[0], (_Float16)y[1], (_Float16)y[2], (_Float16)y[3] };
  _Float16* dst = (tensor ? Vw : Kw) + (size_t)bht * 4096 + (size_t)loc * 8;
  *(half8*)dst = h;
}

// ---- per-group online softmax + fp16 pack (deferred cross-lane max) ----
static __device__ __forceinline__ void softmax_pack(f32x4 (&s)[4], float& m_run,
                                                    f32x4& l_acc, f32x4 (&o)[4],
                                                    half8 (&pb)[2]) {
  float plm;
  {
    float a0 = MAX3(s[0][0], s[0][1], s[0][2]);
    float a1 = MAX3(s[0][3], s[1][0], s[1][1]);
    float a2 = MAX3(s[1][2], s[1][3], s[2][0]);
    float a3 = MAX3(s[2][1], s[2][2], s[2][3]);
    float a4 = MAX3(s[3][0], s[3][1], s[3][2]);
    plm = fmaxf(MAX3(a0, a1, a2), MAX3(a3, a4, s[3][3]));
  }
  float p[16];
  if (__any(plm > m_run + 8.f)) {   // rare: true rescale path
    float pmax = fmaxf(plm, __shfl_xor(plm, 16, 64));
    pmax = fmaxf(pmax, __shfl_xor(pmax, 32, 64));
    const float mnew  = fmaxf(m_run, pmax);
    const float alpha = EXP2(m_run - mnew);
    m_run = mnew;
#pragma unroll
    for (int i = 0; i < 16; ++i)
      p[i] = EXP2(s[i >> 2][i & 3] - mnew);
    l_acc[0] *= alpha;
#pragma unroll
    for (int dt = 0; dt < 4; ++dt) {
      o[dt][0] *= alpha; o[dt][1] *= alpha;
      o[dt][2] *= alpha; o[dt][3] *= alpha;
    }
  } else {                          // common: packed-pair subtract (v_pk_add_f32)
    const float2v mm = { m_run, m_run };
#pragma unroll
    for (int i = 0; i < 16; i += 2) {
      float2v sv = { s[i >> 2][i & 3], s[(i + 1) >> 2][(i + 1) & 3] };
      float2v dv = sv - mm;
      p[i]     = EXP2(dv[0]);
      p[i + 1] = EXP2(dv[1]);
    }
  }
#pragma unroll
  for (int kc = 0; kc < 2; ++kc) {
    fp16x2 x0 = __builtin_amdgcn_cvt_pkrtz(p[8 * kc + 0], p[8 * kc + 1]);
    fp16x2 x1 = __builtin_amdgcn_cvt_pkrtz(p[8 * kc + 2], p[8 * kc + 3]);
    fp16x2 x2 = __builtin_amdgcn_cvt_pkrtz(p[8 * kc + 4], p[8 * kc + 5]);
    fp16x2 x3 = __builtin_amdgcn_cvt_pkrtz(p[8 * kc + 6], p[8 * kc + 7]);
    half8 pk = { (_Float16)x0[0], (_Float16)x0[1], (_Float16)x1[0], (_Float16)x1[1],
                 (_Float16)x2[0], (_Float16)x2[1], (_Float16)x3[0], (_Float16)x3[1] };
    pb[kc] = pk;
  }
}

// ---------------- main: QBLK=128, 4 waves, 4-slot ring, T15 pipeline,
// ---------------- XCD-swizzled flat grid, fp16 Q loads.
// RACE-SAFE ring schedule: per tile T: vmcnt(4) -> SBAR_T -> STAGE(T+2).
// Safety: STAGE(T+2) overwrites slot (T+2)&3 holding tile T-2. Every wave's
// reads of tile T-2 (QK ds_reads consumed in ITER(T-2); tr-reads drained at
// lgkmcnt(15) mid-ITER(T-1)) complete BEFORE that wave reaches SBAR_T; the
// writer issues only AFTER passing SBAR_T.
__global__ __launch_bounds__(256, 2)
void fa_fwd2(const _Float16* __restrict__ Qw, const _Float16* __restrict__ Kw,
             const _Float16* __restrict__ Vw, float* __restrict__ Og) {
  __shared__ __attribute__((aligned(128))) _Float16 Klds[4][4096];
  __shared__ __attribute__((aligned(128))) _Float16 Vlds[4][4096];

  const int tid  = (int)threadIdx.x;
  const int wid  = tid >> 6;
  const int lane = tid & 63;
  const int g    = lane >> 4;
  const int c    = lane & 15;

  // XCD swizzle: all 16 q-tiles of one bh share the same XCD L2 (m09 round-robin).
  const int f     = (int)blockIdx.x;
  const int bh    = (f & 7) * 4 + (f >> 7);
  const int qtile = (f >> 3) & 15;
  const size_t base = (size_t)bh * (S_LEN * D_DIM);

  const int qrowA = qtile * QBLK + wid * 16 + c;
  const int qrowB = qrowA + 64;
  half8 qfA[2], qfB[2];
#pragma unroll
  for (int kt = 0; kt < 2; ++kt) {
    qfA[kt] = *(const half8*)&Qw[base + (size_t)qrowA * D_DIM + kt * 32 + 8 * g];
    qfB[kt] = *(const half8*)&Qw[base + (size_t)qrowB * D_DIM + kt * 32 + 8 * g];
  }

  const f32x4 zero4 = {0.f, 0.f, 0.f, 0.f};
  f32x4 o_accA[4], o_accB[4];
#pragma unroll
  for (int i = 0; i < 4; ++i) { o_accA[i] = zero4; o_accB[i] = zero4; }
  f32x4 l_accA = zero4, l_accB = zero4;
  const half8 ones8 = { (_Float16)1.f, (_Float16)1.f, (_Float16)1.f, (_Float16)1.f,
                        (_Float16)1.f, (_Float16)1.f, (_Float16)1.f, (_Float16)1.f };
  float m_runA = -1.0e30f, m_runB = -1.0e30f;

  const char* kbase = (const char*)Kw + ((size_t)(bh * NT) << 13);
  const char* vbase = (const char*)Vw + ((size_t)(bh * NT) << 13);
  const int woff = wid * 2048 + lane * 16;

#define STAGE(b, t) do { \
    const char* ks_ = kbase + ((size_t)(t) << 13) + woff; \
    const char* vs_ = vbase + ((size_t)(t) << 13) + woff; \
    glds16(ks_,        &Klds[(b)][wid * 1024]); \
    glds16(ks_ + 1024, &Klds[(b)][wid * 1024 + 512]); \
    glds16(vs_,        &Vlds[(b)][wid * 1024]); \
    glds16(vs_ + 1024, &Vlds[(b)][wid * 1024 + 512]); \
  } while (0)

  const uint32_t vtb0 = (uint32_t)(uintptr_t)(&Vlds[0][0]) + 1024u * (uint32_t)g + 8u * (uint32_t)c;

  // pipeline register state: two sets (prev/cur alternate by tile parity)
  half4 vr0[16], vr1[16];
  half8 pbA0[2], pbB0[2], pbA1[2], pbB1[2];

#define TRRD_SET(VR, vt) do { \
    asm volatile("ds_read_b64_tr_b16 %0, %1 offset:0"    : "=v"(VR[0])  : "v"(vt)); \
    asm volatile("ds_read_b64_tr_b16 %0, %1 offset:128"  : "=v"(VR[1])  : "v"(vt)); \
    asm volatile("ds_read_b64_tr_b16 %0, %1 offset:256"  : "=v"(VR[2])  : "v"(vt)); \
    asm volatile("ds_read_b64_tr_b16 %0, %1 offset:384"  : "=v"(VR[3])  : "v"(vt)); \
    asm volatile("ds_read_b64_tr_b16 %0, %1 offset:512"  : "=v"(VR[4])  : "v"(vt)); \
    asm volatile("ds_read_b64_tr_b16 %0, %1 offset:640"  : "=v"(VR[5])  : "v"(vt)); \
    asm volatile("ds_read_b64_tr_b16 %0, %1 offset:768"  : "=v"(VR[6])  : "v"(vt)); \
    asm volatile("ds_read_b64_tr_b16 %0, %1 offset:896"  : "=v"(VR[7])  : "v"(vt)); \
    asm volatile("ds_read_b64_tr_b16 %0, %1 offset:4096" : "=v"(VR[8])  : "v"(vt)); \
    asm volatile("ds_read_b64_tr_b16 %0, %1 offset:4224" : "=v"(VR[9])  : "v"(vt)); \
    asm volatile("ds_read_b64_tr_b16 %0, %1 offset:4352" : "=v"(VR[10]) : "v"(vt)); \
    asm volatile("ds_read_b64_tr_b16 %0, %1 offset:4480" : "=v"(VR[11]) : "v"(vt)); \
    asm volatile("ds_read_b64_tr_b16 %0, %1 offset:4608" : "=v"(VR[12]) : "v"(vt)); \
    asm volatile("ds_read_b64_tr_b16 %0, %1 offset:4736" : "=v"(VR[13]) : "v"(vt)); \
    asm volatile("ds_read_b64_tr_b16 %0, %1 offset:4864" : "=v"(VR[14]) : "v"(vt)); \
    asm volatile("ds_read_b64_tr_b16 %0, %1 offset:4992" : "=v"(VR[15]) : "v"(vt)); \
  } while (0)

#define PV_BLOCK(VR, PBA, PBB) do { \
    __builtin_amdgcn_s_setprio(1); \
    _Pragma("unroll") \
    for (int kc = 0; kc < 2; ++kc) { \
      _Pragma("unroll") \
      for (int dt = 0; dt < 4; ++dt) { \
        half8 vf = __builtin_shufflevector(VR[kc * 8 + dt], VR[kc * 8 + 4 + dt], \
                                           0, 1, 2, 3, 4, 5, 6, 7); \
        o_accA[dt] = __builtin_amdgcn_mfma_f32_16x16x32_f16(vf, PBA[kc], o_accA[dt], 0, 0, 0); \
        o_accB[dt] = __builtin_amdgcn_mfma_f32_16x16x32_f16(vf, PBB[kc], o_accB[dt], 0, 0, 0); \
      } \
      l_accA = __builtin_amdgcn_mfma_f32_16x16x32_f16(ones8, PBA[kc], l_accA, 0, 0, 0); \
      l_accB = __builtin_amdgcn_mfma_f32_16x16x32_f16(ones8, PBB[kc], l_accB, 0, 0, 0); \
    } \
    __builtin_amdgcn_s_setprio(0); \
  } while (0)

  // ITER(T): vmcnt -> SBAR -> STAGE(T+2) -> QK(T) -> TRRD(T) -> [PV(T-1)] -> softmax(T)
#define ITER(T, VRC, PBAC, PBBC, DO_PV, VRP, PBAP, PBBP) do { \
    if ((T) + 1 < NT) { \
      asm volatile("s_waitcnt vmcnt(4)" ::: "memory"); \
    } else { \
      asm volatile("s_waitcnt vmcnt(0)" ::: "memory"); \
    } \
    __builtin_amdgcn_sched_barrier(0); \
    SBAR(); \
    if ((T) + 2 < NT) STAGE(((T) + 2) & 3, (T) + 2); \
    const _Float16* kcur = &Klds[(T) & 3][0]; \
    const uint32_t vt = vtb0 + (uint32_t)(((T) & 3) << 13); \
    f32x4 sA[4], sB[4]; \
    _Pragma("unroll") \
    for (int ct = 0; ct < 4; ++ct) { sA[ct] = zero4; sB[ct] = zero4; } \
    __builtin_amdgcn_s_setprio(1); \
    _Pragma("unroll") \
    for (int ct = 0; ct < 4; ++ct) { \
      _Pragma("unroll") \
      for (int kt = 0; kt < 2; ++kt) { \
        half8 kb = *(half8*)&kcur[(ct * 16 + c) * 64 + (((4 * kt + g) ^ (c & 7)) << 3)]; \
        sA[ct] = __builtin_amdgcn_mfma_f32_16x16x32_f16(kb, qfA[kt], sA[ct], 0, 0, 0); \
        sB[ct] = __builtin_amdgcn_mfma_f32_16x16x32_f16(kb, qfB[kt], sB[ct], 0, 0, 0); \
      } \
    } \
    __builtin_amdgcn_s_setprio(0); \
    TRRD_SET(VRC, vt); \
    if (DO_PV) { \
      asm volatile("s_waitcnt lgkmcnt(15)" ::: "memory"); /* drains prev's 16 tr-reads */ \
      __builtin_amdgcn_sched_barrier(0); \
      PV_BLOCK(VRP, PBAP, PBBP); \
    } \
    softmax_pack(sA, m_runA, l_accA, o_accA, PBAC); \
    softmax_pack(sB, m_runB, l_accB, o_accB, PBBC); \
  } while (0)

  // drain Q loads so vmcnt arithmetic counts only STAGE loads
  asm volatile("s_waitcnt vmcnt(0)" ::: "memory");
  STAGE(0, 0);
  STAGE(1, 1);

  ITER(0, vr0, pbA0, pbB0, 0, vr1, pbA1, pbB1);
  for (int t = 1; t + 1 < NT; t += 2) {
    ITER(t,     vr1, pbA1, pbB1, 1, vr0, pbA0, pbB0);
    ITER(t + 1, vr0, pbA0, pbB0, 1, vr1, pbA1, pbB1);
  }
  ITER(NT - 1, vr1, pbA1, pbB1, 1, vr0, pbA0, pbB0);
  // drain final tile's tr-reads, then last PV
  asm volatile("s_waitcnt lgkmcnt(0)" ::: "memory");
  __builtin_amdgcn_sched_barrier(0);
  PV_BLOCK(vr1, pbA1, pbB1);
#undef ITER
#undef PV_BLOCK
#undef TRRD_SET
#undef STAGE

  const float invA = 1.0f / l_accA[0];
  const float invB = 1.0f / l_accB[0];
#pragma unroll
  for (int dt = 0; dt < 4; ++dt) {
    float4v wA = { o_accA[dt][0] * invA, o_accA[dt][1] * invA,
                   o_accA[dt][2] * invA, o_accA[dt][3] * invA };
    *(float4v*)&Og[base + (size_t)qrowA * D_DIM + dt * 16 + g * 4] = wA;
    float4v wB = { o_accB[dt][0] * invB, o_accB[dt][1] * invB,
                   o_accB[dt][2] * invB, o_accB[dt][3] * invB };
    *(float4v*)&Og[base + (size_t)qrowB * D_DIM + dt * 16 + g * 4] = wB;
  }
}

// ---------------- fallback (round-5 kernel) if ws too small ----------------
__global__ __launch_bounds__(256)
void fa_fwd_fb(const float* __restrict__ Qg, const float* __restrict__ Kg,
               const float* __restrict__ Vg, float* __restrict__ Og) {
  __shared__ _Float16 Klds[KVBLK * KSTR];
  __shared__ __attribute__((aligned(128))) _Float16 Vlds[KVBLK * D_DIM];

  const int tid  = (int)threadIdx.x;
  const int wid  = tid >> 6;
  const int lane = tid & 63;
  const int g    = lane >> 4;
  const int c    = lane & 15;

  const int qtile = (int)blockIdx.x;
  const int bh    = (int)blockIdx.y;
  const size_t base = (size_t)bh * (S_LEN * D_DIM);

  const int qrow = qtile * 64 + wid * 16 + c;
  half8 qf[2];
#pragma unroll
  for (int kt = 0; kt < 2; ++kt) {
    const float* qp = Qg + base + (size_t)qrow * D_DIM + kt * 32 + 8 * g;
    float4v a = *(const float4v*)qp;
    float4v b = *(const float4v*)(qp + 4);
    half8 q;
    q[0] = (_Float16)(a[0] * QSCALE); q[1] = (_Float16)(a[1] * QSCALE);
    q[2] = (_Float16)(a[2] * QSCALE); q[3] = (_Float16)(a[3] * QSCALE);
    q[4] = (_Float16)(b[0] * QSCALE); q[5] = (_Float16)(b[1] * QSCALE);
    q[6] = (_Float16)(b[2] * QSCALE); q[7] = (_Float16)(b[3] * QSCALE);
    qf[kt] = q;
  }

  const f32x4 zero4 = {0.f, 0.f, 0.f, 0.f};
  f32x4 o_acc[4];
#pragma unroll
  for (int i = 0; i < 4; ++i) o_acc[i] = zero4;
  float m_run = -1.0e30f, l_run = 0.f;

  const int srow = tid >> 4;
  const int scol = (tid & 15) * 4;
  const int vgi = tid >> 4;
  const int vlg = tid & 15;
  const int vk  = vgi * 4 + (vlg >> 2);
  const int vsub = 8 * (vgi & 3) + 4 * ((vgi >> 2) & 1) + 32 * (vgi >> 3);
  const uint32_t vtb = (uint32_t)(uintptr_t)(&Vlds[0]) + 1024u * (uint32_t)g + 8u * (uint32_t)c;

  for (int t = 0; t < NT; ++t) {
    const int kv0 = t * KVBLK;
    __syncthreads();
#pragma unroll
    for (int rr = 0; rr < 4; ++rr) {
      const int row = srow + rr * 16;
      const float* kp = Kg + base + (size_t)(kv0 + row) * D_DIM + scol;
      float4v kx = *(const float4v*)kp;
      half4 kh = { (_Float16)kx[0], (_Float16)kx[1], (_Float16)kx[2], (_Float16)kx[3] };
      *(half4*)&Klds[row * KSTR + scol] = kh;
    }
#pragma unroll
    for (int it = 0; it < 4; ++it) {
      const int d = it * 16 + (vlg & 3) * 4;
      const float* vp = Vg + base + (size_t)(kv0 + vk) * D_DIM + d;
      float4v vx = *(const float4v*)vp;
      half4 vh = { (_Float16)vx[0], (_Float16)vx[1], (_Float16)vx[2], (_Float16)vx[3] };
      *(half4*)&Vlds[(vsub + it) * 64 + (vlg >> 2) * 16 + (vlg & 3) * 4] = vh;
    }
    __syncthreads();

    f32x4 s_acc[4];
#pragma unroll
    for (int ct = 0; ct < 4; ++ct) s_acc[ct] = zero4;
#pragma unroll
    for (int ct = 0; ct < 4; ++ct) {
#pragma unroll
      for (int kt = 0; kt < 2; ++kt) {
        half8 kb = *(half8*)&Klds[(ct * 16 + c) * KSTR + kt * 32 + 8 * g];
        s_acc[ct] = __builtin_amdgcn_mfma_f32_16x16x32_f16(kb, qf[kt], s_acc[ct], 0, 0, 0);
      }
    }

    float pmax = -1.0e30f;
#pragma unroll
    for (int ct = 0; ct < 4; ++ct)
#pragma unroll
      for (int r = 0; r < 4; ++r) pmax = fmaxf(pmax, s_acc[ct][r]);
    pmax = fmaxf(pmax, __shfl_xor(pmax, 16, 64));
    pmax = fmaxf(pmax, __shfl_xor(pmax, 32, 64));
    const float mnew  = fmaxf(m_run, pmax);
    const float alpha = exp2f(m_run - mnew);
    m_run = mnew;

    float p[16];
    float psum = 0.f;
#pragma unroll
    for (int i = 0; i < 16; ++i) {
      p[i] = exp2f(s_acc[i >> 2][i & 3] - mnew);
      psum += p[i];
    }
    psum += __shfl_xor(psum, 16, 64);
    psum += __shfl_xor(psum, 32, 64);
    l_run = l_run * alpha + psum;
#pragma unroll
    for (int dt = 0; dt < 4; ++dt) {
      o_acc[dt][0] *= alpha; o_acc[dt][1] *= alpha;
      o_acc[dt][2] *= alpha; o_acc[dt][3] *= alpha;
    }

    half8 pb[2];
#pragma unroll
    for (int kc = 0; kc < 2; ++kc) {
      fp16x2 x0 = __builtin_amdgcn_cvt_pkrtz(p[8 * kc + 0], p[8 * kc + 1]);
      fp16x2 x1 = __builtin_amdgcn_cvt_pkrtz(p[8 * kc + 2], p[8 * kc + 3]);
      fp16x2 x2 = __builtin_amdgcn_cvt_pkrtz(p[8 * kc + 4], p[8 * kc + 5]);
      fp16x2 x3 = __builtin_amdgcn_cvt_pkrtz(p[8 * kc + 6], p[8 * kc + 7]);
      half8 pk = { (_Float16)x0[0], (_Float16)x0[1], (_Float16)x1[0], (_Float16)x1[1],
                   (_Float16)x2[0], (_Float16)x2[1], (_Float16)x3[0], (_Float16)x3[1] };
      pb[kc] = pk;
    }

    half4 vr[16];
#define TRRD(i, offstr) \
    asm volatile("ds_read_b64_tr_b16 %0, %1 offset:" offstr : "=v"(vr[i]) : "v"(vtb))
    TRRD(0,  "0");    TRRD(1,  "128");  TRRD(2,  "256");  TRRD(3,  "384");
    TRRD(4,  "512");  TRRD(5,  "640");  TRRD(6,  "768");  TRRD(7,  "896");
    TRRD(8,  "4096"); TRRD(9,  "4224"); TRRD(10, "4352"); TRRD(11, "4480");
    TRRD(12, "4608"); TRRD(13, "4736"); TRRD(14, "4864"); TRRD(15, "4992");
#undef TRRD
    asm volatile("s_waitcnt lgkmcnt(0)" ::: "memory");
    __builtin_amdgcn_sched_barrier(0);

#pragma unroll
    for (int kc = 0; kc < 2; ++kc) {
#pragma unroll
      for (int dt = 0; dt < 4; ++dt) {
        half8 vf = __builtin_shufflevector(vr[kc * 8 + dt], vr[kc * 8 + 4 + dt],
                                           0, 1, 2, 3, 4, 5, 6, 7);
        o_acc[dt] = __builtin_amdgcn_mfma_f32_16x16x32_f16(vf, pb[kc], o_acc[dt], 0, 0, 0);
      }
    }
  }

  const float invl = 1.0f / l_run;
#pragma unroll
  for (int dt = 0; dt < 4; ++dt) {
    float4v w = { o_acc[dt][0] * invl, o_acc[dt][1] * invl,
                  o_acc[dt][2] * invl, o_acc[dt][3] * invl };
    *(float4v*)&Og[base + (size_t)qrow * D_DIM + dt * 16 + g * 4] = w;
  }
}

extern "C" void kernel_launch(void* const* d_in, const int* in_sizes, int n_in,
                              void* d_out, int out_size, void* d_ws, size_t ws_size,
                              hipStream_t stream) {
  const float* Q = (const float*)d_in[0];
  const float* K = (const float*)d_in[1];
  const float* V = (const float*)d_in[2];
  float* O = (float*)d_out;
  // ws layout: Kw 8MB | Vw 8MB | Qw 8MB = 25,165,824 B
  if (ws_size >= (size_t)28 * 1024 * 1024) {
    _Float16* Kw = (_Float16*)d_ws;
    _Float16* Vw = Kw + (size_t)NBH * S_LEN * D_DIM;
    _Float16* Qw = Vw + (size_t)NBH * S_LEN * D_DIM;
    hipLaunchKernelGGL(cvt_pack, dim3(6144), dim3(256), 0, stream, K, V, Q, Kw, Vw, Qw);
    hipLaunchKernelGGL(fa_fwd2, dim3((S_LEN / QBLK) * NBH), dim3(256), 0, stream, Qw, Kw, Vw, O);
  } else {
    hipLaunchKernelGGL(fa_fwd_fb, dim3(S_LEN / 64, NBH), dim3(256), 0, stream, Q, K, V, O);
  }
}

// Round 19
// 61.200 us; speedup vs baseline: 1.0610x; 1.0610x over previous
//
#include <hip/hip_runtime.h>
#include <stdint.h>

typedef _Float16 half8 __attribute__((ext_vector_type(8)));
typedef _Float16 half4 __attribute__((ext_vector_type(4)));
typedef __fp16 fp16x2 __attribute__((ext_vector_type(2)));
typedef float f32x4 __attribute__((ext_vector_type(4)));
typedef float float4v __attribute__((ext_vector_type(4)));

#define S_LEN 2048
#define D_DIM 64
#define QBLK 128             // 2 q-groups of 16 rows per wave, 4 waves
#define KVBLK 64
#define NT (S_LEN / KVBLK)   // 32 kv tiles
#define NBH 32               // b*h
#define QSCALE 0.18033688f   // 0.125 * log2(e): softmax in base-2 domain
#define KSTR 72              // fallback-kernel K stride

#if __has_builtin(__builtin_amdgcn_exp2f)
#define EXP2(x) __builtin_amdgcn_exp2f(x)
#else
#define EXP2(x) exp2f(x)
#endif
#define MAX3(a, b, c) fmaxf(fmaxf((a), (b)), (c))

static __device__ __forceinline__ void glds16(const void* g, void* l) {
  __builtin_amdgcn_global_load_lds(
      (__attribute__((address_space(1))) void*)(g),
      (__attribute__((address_space(3))) void*)(l), 16, 0, 0);
}
#define SBAR() do { asm volatile("" ::: "memory"); __builtin_amdgcn_s_barrier(); asm volatile("" ::: "memory"); } while (0)

// ---------------- pre-pass: fp32 K,V -> fp16 LDS-image layout in ws ----------------
__global__ __launch_bounds__(256)
void cvt_pack(const float* __restrict__ Kg, const float* __restrict__ Vg,
              _Float16* __restrict__ Kw, _Float16* __restrict__ Vw) {
  const int id = (int)(blockIdx.x * 256 + threadIdx.x);
  const int tensor = id >> 19;
  const int cid = id & 0x7FFFF;
  const int bht = cid >> 9;       // bh*NT + t
  const int bh = bht >> 5, t = bht & 31;
  const int loc = cid & 511;
  const int a = loc >> 3;
  const int s = loc & 7;
  size_t srcoff;
  if (tensor == 0) {
    const int r = a;
    srcoff = (size_t)bh * (S_LEN * D_DIM) + (size_t)(t * 64 + r) * D_DIM + 8 * (s ^ (r & 7));
  } else {
    const int TI = a, c2 = s;
    const int it = TI & 3;
    const int vgi = ((TI >> 3) & 3) | (((TI >> 2) & 1) << 2) | (((TI >> 5) & 1) << 3);
    const int kq = c2 >> 1, d8 = (c2 & 1) * 8;
    srcoff = (size_t)bh * (S_LEN * D_DIM) + (size_t)(t * 64 + 4 * vgi + kq) * D_DIM + it * 16 + d8;
  }
  const float* src = (tensor ? Vg : Kg) + srcoff;
  float4v x = *(const float4v*)src;
  float4v y = *(const float4v*)(src + 4);
  half8 h = { (_Float16)x[0], (_Float16)x[1], (_Float16)x[2], (_Float16)x[3],
              (_Float16)y[0], (_Float16)y[1], (_Float16)y[2], (_Float16)y[3] };
  _Float16* dst = (tensor ? Vw : Kw) + (size_t)bht * 4096 + (size_t)loc * 8;
  *(half8*)dst = h;
}

// ---- per-group online softmax + fp16 pack (deferred cross-lane max) ----
static __device__ __forceinline__ void softmax_pack(f32x4 (&s)[4], float& m_run,
                                                    f32x4& l_acc, f32x4 (&o)[4],
                                                    half8 (&pb)[2]) {
  float plm;
  {
    float a0 = MAX3(s[0][0], s[0][1], s[0][2]);
    float a1 = MAX3(s[0][3], s[1][0], s[1][1]);
    float a2 = MAX3(s[1][2], s[1][3], s[2][0]);
    float a3 = MAX3(s[2][1], s[2][2], s[2][3]);
    float a4 = MAX3(s[3][0], s[3][1], s[3][2]);
    plm = fmaxf(MAX3(a0, a1, a2), MAX3(a3, a4, s[3][3]));
  }
  float p[16];
  if (__any(plm > m_run + 8.f)) {   // rare: true rescale path
    float pmax = fmaxf(plm, __shfl_xor(plm, 16, 64));
    pmax = fmaxf(pmax, __shfl_xor(pmax, 32, 64));
    const float mnew  = fmaxf(m_run, pmax);
    const float alpha = EXP2(m_run - mnew);
    m_run = mnew;
#pragma unroll
    for (int i = 0; i < 16; ++i)
      p[i] = EXP2(s[i >> 2][i & 3] - mnew);
    l_acc[0] *= alpha;
#pragma unroll
    for (int dt = 0; dt < 4; ++dt) {
      o[dt][0] *= alpha; o[dt][1] *= alpha;
      o[dt][2] *= alpha; o[dt][3] *= alpha;
    }
  } else {                          // common: no rescale, no cross-lane reduce
#pragma unroll
    for (int i = 0; i < 16; ++i)
      p[i] = EXP2(s[i >> 2][i & 3] - m_run);
  }
#pragma unroll
  for (int kc = 0; kc < 2; ++kc) {
    fp16x2 x0 = __builtin_amdgcn_cvt_pkrtz(p[8 * kc + 0], p[8 * kc + 1]);
    fp16x2 x1 = __builtin_amdgcn_cvt_pkrtz(p[8 * kc + 2], p[8 * kc + 3]);
    fp16x2 x2 = __builtin_amdgcn_cvt_pkrtz(p[8 * kc + 4], p[8 * kc + 5]);
    fp16x2 x3 = __builtin_amdgcn_cvt_pkrtz(p[8 * kc + 6], p[8 * kc + 7]);
    half8 pk = { (_Float16)x0[0], (_Float16)x0[1], (_Float16)x1[0], (_Float16)x1[1],
                 (_Float16)x2[0], (_Float16)x2[1], (_Float16)x3[0], (_Float16)x3[1] };
    pb[kc] = pk;
  }
}

// ---------------- main: QBLK=128, 4 waves, 4-slot ring, T15 pipeline,
// ---------------- XCD-swizzled flat grid (16 q-tiles of one bh share one XCD L2).
// RACE-SAFE ring schedule: per tile T: vmcnt(4) -> SBAR_T -> STAGE(T+2).
// Safety: STAGE(T+2) overwrites slot (T+2)&3 holding tile T-2. Every wave's
// reads of tile T-2 (QK ds_reads consumed in ITER(T-2); tr-reads drained at
// lgkmcnt(15) mid-ITER(T-1)) complete BEFORE that wave reaches SBAR_T; the
// writer issues only AFTER passing SBAR_T.
__global__ __launch_bounds__(256, 2)
void fa_fwd2(const float* __restrict__ Qg, const _Float16* __restrict__ Kw,
             const _Float16* __restrict__ Vw, float* __restrict__ Og) {
  __shared__ __attribute__((aligned(128))) _Float16 Klds[4][4096];
  __shared__ __attribute__((aligned(128))) _Float16 Vlds[4][4096];

  const int tid  = (int)threadIdx.x;
  const int wid  = tid >> 6;
  const int lane = tid & 63;
  const int g    = lane >> 4;
  const int c    = lane & 15;

  // XCD swizzle: all 16 q-tiles of one bh share the same XCD L2 (m09 round-robin).
  const int f     = (int)blockIdx.x;
  const int bh    = (f & 7) * 4 + (f >> 7);
  const int qtile = (f >> 3) & 15;
  const size_t base = (size_t)bh * (S_LEN * D_DIM);

  const int qrowA = qtile * QBLK + wid * 16 + c;
  const int qrowB = qrowA + 64;
  half8 qfA[2], qfB[2];
#pragma unroll
  for (int kt = 0; kt < 2; ++kt) {
    const float* qpA = Qg + base + (size_t)qrowA * D_DIM + kt * 32 + 8 * g;
    const float* qpB = Qg + base + (size_t)qrowB * D_DIM + kt * 32 + 8 * g;
    float4v a0 = *(const float4v*)qpA;
    float4v a1 = *(const float4v*)(qpA + 4);
    float4v b0 = *(const float4v*)qpB;
    float4v b1 = *(const float4v*)(qpB + 4);
    half8 qa = { (_Float16)(a0[0] * QSCALE), (_Float16)(a0[1] * QSCALE),
                 (_Float16)(a0[2] * QSCALE), (_Float16)(a0[3] * QSCALE),
                 (_Float16)(a1[0] * QSCALE), (_Float16)(a1[1] * QSCALE),
                 (_Float16)(a1[2] * QSCALE), (_Float16)(a1[3] * QSCALE) };
    half8 qb = { (_Float16)(b0[0] * QSCALE), (_Float16)(b0[1] * QSCALE),
                 (_Float16)(b0[2] * QSCALE), (_Float16)(b0[3] * QSCALE),
                 (_Float16)(b1[0] * QSCALE), (_Float16)(b1[1] * QSCALE),
                 (_Float16)(b1[2] * QSCALE), (_Float16)(b1[3] * QSCALE) };
    qfA[kt] = qa; qfB[kt] = qb;
  }

  const f32x4 zero4 = {0.f, 0.f, 0.f, 0.f};
  f32x4 o_accA[4], o_accB[4];
#pragma unroll
  for (int i = 0; i < 4; ++i) { o_accA[i] = zero4; o_accB[i] = zero4; }
  f32x4 l_accA = zero4, l_accB = zero4;
  const half8 ones8 = { (_Float16)1.f, (_Float16)1.f, (_Float16)1.f, (_Float16)1.f,
                        (_Float16)1.f, (_Float16)1.f, (_Float16)1.f, (_Float16)1.f };
  float m_runA = -1.0e30f, m_runB = -1.0e30f;

  const char* kbase = (const char*)Kw + ((size_t)(bh * NT) << 13);
  const char* vbase = (const char*)Vw + ((size_t)(bh * NT) << 13);
  const int woff = wid * 2048 + lane * 16;

#define STAGE(b, t) do { \
    const char* ks_ = kbase + ((size_t)(t) << 13) + woff; \
    const char* vs_ = vbase + ((size_t)(t) << 13) + woff; \
    glds16(ks_,        &Klds[(b)][wid * 1024]); \
    glds16(ks_ + 1024, &Klds[(b)][wid * 1024 + 512]); \
    glds16(vs_,        &Vlds[(b)][wid * 1024]); \
    glds16(vs_ + 1024, &Vlds[(b)][wid * 1024 + 512]); \
  } while (0)

  const uint32_t vtb0 = (uint32_t)(uintptr_t)(&Vlds[0][0]) + 1024u * (uint32_t)g + 8u * (uint32_t)c;

  // pipeline register state: two sets (prev/cur alternate by tile parity)
  half4 vr0[16], vr1[16];
  half8 pbA0[2], pbB0[2], pbA1[2], pbB1[2];

#define TRRD_SET(VR, vt) do { \
    asm volatile("ds_read_b64_tr_b16 %0, %1 offset:0"    : "=v"(VR[0])  : "v"(vt)); \
    asm volatile("ds_read_b64_tr_b16 %0, %1 offset:128"  : "=v"(VR[1])  : "v"(vt)); \
    asm volatile("ds_read_b64_tr_b16 %0, %1 offset:256"  : "=v"(VR[2])  : "v"(vt)); \
    asm volatile("ds_read_b64_tr_b16 %0, %1 offset:384"  : "=v"(VR[3])  : "v"(vt)); \
    asm volatile("ds_read_b64_tr_b16 %0, %1 offset:512"  : "=v"(VR[4])  : "v"(vt)); \
    asm volatile("ds_read_b64_tr_b16 %0, %1 offset:640"  : "=v"(VR[5])  : "v"(vt)); \
    asm volatile("ds_read_b64_tr_b16 %0, %1 offset:768"  : "=v"(VR[6])  : "v"(vt)); \
    asm volatile("ds_read_b64_tr_b16 %0, %1 offset:896"  : "=v"(VR[7])  : "v"(vt)); \
    asm volatile("ds_read_b64_tr_b16 %0, %1 offset:4096" : "=v"(VR[8])  : "v"(vt)); \
    asm volatile("ds_read_b64_tr_b16 %0, %1 offset:4224" : "=v"(VR[9])  : "v"(vt)); \
    asm volatile("ds_read_b64_tr_b16 %0, %1 offset:4352" : "=v"(VR[10]) : "v"(vt)); \
    asm volatile("ds_read_b64_tr_b16 %0, %1 offset:4480" : "=v"(VR[11]) : "v"(vt)); \
    asm volatile("ds_read_b64_tr_b16 %0, %1 offset:4608" : "=v"(VR[12]) : "v"(vt)); \
    asm volatile("ds_read_b64_tr_b16 %0, %1 offset:4736" : "=v"(VR[13]) : "v"(vt)); \
    asm volatile("ds_read_b64_tr_b16 %0, %1 offset:4864" : "=v"(VR[14]) : "v"(vt)); \
    asm volatile("ds_read_b64_tr_b16 %0, %1 offset:4992" : "=v"(VR[15]) : "v"(vt)); \
  } while (0)

#define PV_BLOCK(VR, PBA, PBB) do { \
    __builtin_amdgcn_s_setprio(1); \
    _Pragma("unroll") \
    for (int kc = 0; kc < 2; ++kc) { \
      _Pragma("unroll") \
      for (int dt = 0; dt < 4; ++dt) { \
        half8 vf = __builtin_shufflevector(VR[kc * 8 + dt], VR[kc * 8 + 4 + dt], \
                                           0, 1, 2, 3, 4, 5, 6, 7); \
        o_accA[dt] = __builtin_amdgcn_mfma_f32_16x16x32_f16(vf, PBA[kc], o_accA[dt], 0, 0, 0); \
        o_accB[dt] = __builtin_amdgcn_mfma_f32_16x16x32_f16(vf, PBB[kc], o_accB[dt], 0, 0, 0); \
      } \
      l_accA = __builtin_amdgcn_mfma_f32_16x16x32_f16(ones8, PBA[kc], l_accA, 0, 0, 0); \
      l_accB = __builtin_amdgcn_mfma_f32_16x16x32_f16(ones8, PBB[kc], l_accB, 0, 0, 0); \
    } \
    __builtin_amdgcn_s_setprio(0); \
  } while (0)

  // ITER(T): vmcnt -> SBAR -> STAGE(T+2) -> QK(T) -> TRRD(T) -> [PV(T-1)] -> softmax(T)
#define ITER(T, VRC, PBAC, PBBC, DO_PV, VRP, PBAP, PBBP) do { \
    if ((T) + 1 < NT) { \
      asm volatile("s_waitcnt vmcnt(4)" ::: "memory"); \
    } else { \
      asm volatile("s_waitcnt vmcnt(0)" ::: "memory"); \
    } \
    __builtin_amdgcn_sched_barrier(0); \
    SBAR(); \
    if ((T) + 2 < NT) STAGE(((T) + 2) & 3, (T) + 2); \
    const _Float16* kcur = &Klds[(T) & 3][0]; \
    const uint32_t vt = vtb0 + (uint32_t)(((T) & 3) << 13); \
    f32x4 sA[4], sB[4]; \
    _Pragma("unroll") \
    for (int ct = 0; ct < 4; ++ct) { sA[ct] = zero4; sB[ct] = zero4; } \
    __builtin_amdgcn_s_setprio(1); \
    _Pragma("unroll") \
    for (int ct = 0; ct < 4; ++ct) { \
      _Pragma("unroll") \
      for (int kt = 0; kt < 2; ++kt) { \
        half8 kb = *(half8*)&kcur[(ct * 16 + c) * 64 + (((4 * kt + g) ^ (c & 7)) << 3)]; \
        sA[ct] = __builtin_amdgcn_mfma_f32_16x16x32_f16(kb, qfA[kt], sA[ct], 0, 0, 0); \
        sB[ct] = __builtin_amdgcn_mfma_f32_16x16x32_f16(kb, qfB[kt], sB[ct], 0, 0, 0); \
      } \
    } \
    __builtin_amdgcn_s_setprio(0); \
    TRRD_SET(VRC, vt); \
    if (DO_PV) { \
      asm volatile("s_waitcnt lgkmcnt(15)" ::: "memory"); /* drains prev's 16 tr-reads */ \
      __builtin_amdgcn_sched_barrier(0); \
      PV_BLOCK(VRP, PBAP, PBBP); \
    } \
    softmax_pack(sA, m_runA, l_accA, o_accA, PBAC); \
    softmax_pack(sB, m_runB, l_accB, o_accB, PBBC); \
  } while (0)

  // drain Q loads so vmcnt arithmetic counts only STAGE loads
  asm volatile("s_waitcnt vmcnt(0)" ::: "memory");
  STAGE(0, 0);
  STAGE(1, 1);

  ITER(0, vr0, pbA0, pbB0, 0, vr1, pbA1, pbB1);
  for (int t = 1; t + 1 < NT; t += 2) {
    ITER(t,     vr1, pbA1, pbB1, 1, vr0, pbA0, pbB0);
    ITER(t + 1, vr0, pbA0, pbB0, 1, vr1, pbA1, pbB1);
  }
  ITER(NT - 1, vr1, pbA1, pbB1, 1, vr0, pbA0, pbB0);
  // drain final tile's tr-reads, then last PV
  asm volatile("s_waitcnt lgkmcnt(0)" ::: "memory");
  __builtin_amdgcn_sched_barrier(0);
  PV_BLOCK(vr1, pbA1, pbB1);
#undef ITER
#undef PV_BLOCK
#undef TRRD_SET
#undef STAGE

  const float invA = 1.0f / l_accA[0];
  const float invB = 1.0f / l_accB[0];
#pragma unroll
  for (int dt = 0; dt < 4; ++dt) {
    float4v wA = { o_accA[dt][0] * invA, o_accA[dt][1] * invA,
                   o_accA[dt][2] * invA, o_accA[dt][3] * invA };
    *(float4v*)&Og[base + (size_t)qrowA * D_DIM + dt * 16 + g * 4] = wA;
    float4v wB = { o_accB[dt][0] * invB, o_accB[dt][1] * invB,
                   o_accB[dt][2] * invB, o_accB[dt][3] * invB };
    *(float4v*)&Og[base + (size_t)qrowB * D_DIM + dt * 16 + g * 4] = wB;
  }
}

// ---------------- fallback (round-5 kernel) if ws too small ----------------
__global__ __launch_bounds__(256)
void fa_fwd_fb(const float* __restrict__ Qg, const float* __restrict__ Kg,
               const float* __restrict__ Vg, float* __restrict__ Og) {
  __shared__ _Float16 Klds[KVBLK * KSTR];
  __shared__ __attribute__((aligned(128))) _Float16 Vlds[KVBLK * D_DIM];

  const int tid  = (int)threadIdx.x;
  const int wid  = tid >> 6;
  const int lane = tid & 63;
  const int g    = lane >> 4;
  const int c    = lane & 15;

  const int qtile = (int)blockIdx.x;
  const int bh    = (int)blockIdx.y;
  const size_t base = (size_t)bh * (S_LEN * D_DIM);

  const int qrow = qtile * 64 + wid * 16 + c;
  half8 qf[2];
#pragma unroll
  for (int kt = 0; kt < 2; ++kt) {
    const float* qp = Qg + base + (size_t)qrow * D_DIM + kt * 32 + 8 * g;
    float4v a = *(const float4v*)qp;
    float4v b = *(const float4v*)(qp + 4);
    half8 q;
    q[0] = (_Float16)(a[0] * QSCALE); q[1] = (_Float16)(a[1] * QSCALE);
    q[2] = (_Float16)(a[2] * QSCALE); q[3] = (_Float16)(a[3] * QSCALE);
    q[4] = (_Float16)(b[0] * QSCALE); q[5] = (_Float16)(b[1] * QSCALE);
    q[6] = (_Float16)(b[2] * QSCALE); q[7] = (_Float16)(b[3] * QSCALE);
    qf[kt] = q;
  }

  const f32x4 zero4 = {0.f, 0.f, 0.f, 0.f};
  f32x4 o_acc[4];
#pragma unroll
  for (int i = 0; i < 4; ++i) o_acc[i] = zero4;
  float m_run = -1.0e30f, l_run = 0.f;

  const int srow = tid >> 4;
  const int scol = (tid & 15) * 4;
  const int vgi = tid >> 4;
  const int vlg = tid & 15;
  const int vk  = vgi * 4 + (vlg >> 2);
  const int vsub = 8 * (vgi & 3) + 4 * ((vgi >> 2) & 1) + 32 * (vgi >> 3);
  const uint32_t vtb = (uint32_t)(uintptr_t)(&Vlds[0]) + 1024u * (uint32_t)g + 8u * (uint32_t)c;

  for (int t = 0; t < NT; ++t) {
    const int kv0 = t * KVBLK;
    __syncthreads();
#pragma unroll
    for (int rr = 0; rr < 4; ++rr) {
      const int row = srow + rr * 16;
      const float* kp = Kg + base + (size_t)(kv0 + row) * D_DIM + scol;
      float4v kx = *(const float4v*)kp;
      half4 kh = { (_Float16)kx[0], (_Float16)kx[1], (_Float16)kx[2], (_Float16)kx[3] };
      *(half4*)&Klds[row * KSTR + scol] = kh;
    }
#pragma unroll
    for (int it = 0; it < 4; ++it) {
      const int d = it * 16 + (vlg & 3) * 4;
      const float* vp = Vg + base + (size_t)(kv0 + vk) * D_DIM + d;
      float4v vx = *(const float4v*)vp;
      half4 vh = { (_Float16)vx[0], (_Float16)vx[1], (_Float16)vx[2], (_Float16)vx[3] };
      *(half4*)&Vlds[(vsub + it) * 64 + (vlg >> 2) * 16 + (vlg & 3) * 4] = vh;
    }
    __syncthreads();

    f32x4 s_acc[4];
#pragma unroll
    for (int ct = 0; ct < 4; ++ct) s_acc[ct] = zero4;
#pragma unroll
    for (int ct = 0; ct < 4; ++ct) {
#pragma unroll
      for (int kt = 0; kt < 2; ++kt) {
        half8 kb = *(half8*)&Klds[(ct * 16 + c) * KSTR + kt * 32 + 8 * g];
        s_acc[ct] = __builtin_amdgcn_mfma_f32_16x16x32_f16(kb, qf[kt], s_acc[ct], 0, 0, 0);
      }
    }

    float pmax = -1.0e30f;
#pragma unroll
    for (int ct = 0; ct < 4; ++ct)
#pragma unroll
      for (int r = 0; r < 4; ++r) pmax = fmaxf(pmax, s_acc[ct][r]);
    pmax = fmaxf(pmax, __shfl_xor(pmax, 16, 64));
    pmax = fmaxf(pmax, __shfl_xor(pmax, 32, 64));
    const float mnew  = fmaxf(m_run, pmax);
    const float alpha = exp2f(m_run - mnew);
    m_run = mnew;

    float p[16];
    float psum = 0.f;
#pragma unroll
    for (int i = 0; i < 16; ++i) {
      p[i] = exp2f(s_acc[i >> 2][i & 3] - mnew);
      psum += p[i];
    }
    psum += __shfl_xor(psum, 16, 64);
    psum += __shfl_xor(psum, 32, 64);
    l_run = l_run * alpha + psum;
#pragma unroll
    for (int dt = 0; dt < 4; ++dt) {
      o_acc[dt][0] *= alpha; o_acc[dt][1] *= alpha;
      o_acc[dt][2] *= alpha; o_acc[dt][3] *= alpha;
    }

    half8 pb[2];
#pragma unroll
    for (int kc = 0; kc < 2; ++kc) {
      fp16x2 x0 = __builtin_amdgcn_cvt_pkrtz(p[8 * kc + 0], p[8 * kc + 1]);
      fp16x2 x1 = __builtin_amdgcn_cvt_pkrtz(p[8 * kc + 2], p[8 * kc + 3]);
      fp16x2 x2 = __builtin_amdgcn_cvt_pkrtz(p[8 * kc + 4], p[8 * kc + 5]);
      fp16x2 x3 = __builtin_amdgcn_cvt_pkrtz(p[8 * kc + 6], p[8 * kc + 7]);
      half8 pk = { (_Float16)x0[0], (_Float16)x0[1], (_Float16)x1[0], (_Float16)x1[1],
                   (_Float16)x2[0], (_Float16)x2[1], (_Float16)x3[0], (_Float16)x3[1] };
      pb[kc] = pk;
    }

    half4 vr[16];
#define TRRD(i, offstr) \
    asm volatile("ds_read_b64_tr_b16 %0, %1 offset:" offstr : "=v"(vr[i]) : "v"(vtb))
    TRRD(0,  "0");    TRRD(1,  "128");  TRRD(2,  "256");  TRRD(3,  "384");
    TRRD(4,  "512");  TRRD(5,  "640");  TRRD(6,  "768");  TRRD(7,  "896");
    TRRD(8,  "4096"); TRRD(9,  "4224"); TRRD(10, "4352"); TRRD(11, "4480");
    TRRD(12, "4608"); TRRD(13, "4736"); TRRD(14, "4864"); TRRD(15, "4992");
#undef TRRD
    asm volatile("s_waitcnt lgkmcnt(0)" ::: "memory");
    __builtin_amdgcn_sched_barrier(0);

#pragma unroll
    for (int kc = 0; kc < 2; ++kc) {
#pragma unroll
      for (int dt = 0; dt < 4; ++dt) {
        half8 vf = __builtin_shufflevector(vr[kc * 8 + dt], vr[kc * 8 + 4 + dt],
                                           0, 1, 2, 3, 4, 5, 6, 7);
        o_acc[dt] = __builtin_amdgcn_mfma_f32_16x16x32_f16(vf, pb[kc], o_acc[dt], 0, 0, 0);
      }
    }
  }

  const float invl = 1.0f / l_run;
#pragma unroll
  for (int dt = 0; dt < 4; ++dt) {
    float4v w = { o_acc[dt][0] * invl, o_acc[dt][1] * invl,
                  o_acc[dt][2] * invl, o_acc[dt][3] * invl };
    *(float4v*)&Og[base + (size_t)qrow * D_DIM + dt * 16 + g * 4] = w;
  }
}

extern "C" void kernel_launch(void* const* d_in, const int* in_sizes, int n_in,
                              void* d_out, int out_size, void* d_ws, size_t ws_size,
                              hipStream_t stream) {
  const float* Q = (const float*)d_in[0];
  const float* K = (const float*)d_in[1];
  const float* V = (const float*)d_in[2];
  float* O = (float*)d_out;
  if (ws_size >= (size_t)16 * 1024 * 1024) {
    _Float16* Kw = (_Float16*)d_ws;
    _Float16* Vw = Kw + (size_t)NBH * S_LEN * D_DIM;
    hipLaunchKernelGGL(cvt_pack, dim3(4096), dim3(256), 0, stream, K, V, Kw, Vw);
    hipLaunchKernelGGL(fa_fwd2, dim3((S_LEN / QBLK) * NBH), dim3(256), 0, stream, Q, Kw, Vw, O);
  } else {
    hipLaunchKernelGGL(fa_fwd_fb, dim3(S_LEN / 64, NBH), dim3(256), 0, stream, Q, K, V, O);
  }
}

// Round 20
// 59.666 us; speedup vs baseline: 1.0883x; 1.0257x over previous
//
#include <hip/hip_runtime.h>
#include <stdint.h>

typedef _Float16 half8 __attribute__((ext_vector_type(8)));
typedef _Float16 half4 __attribute__((ext_vector_type(4)));
typedef __fp16 fp16x2 __attribute__((ext_vector_type(2)));
typedef float f32x4 __attribute__((ext_vector_type(4)));
typedef float float4v __attribute__((ext_vector_type(4)));

#define S_LEN 2048
#define D_DIM 64
#define QBLK 128             // 2 q-groups of 16 rows per wave, 4 waves
#define KVBLK 64
#define NT (S_LEN / KVBLK)   // 32 kv tiles
#define NBH 32               // b*h
#define QSCALE 0.18033688f   // 0.125 * log2(e): softmax in base-2 domain
#define KSTR 72              // fallback-kernel K stride
#define NEXT5(x) ((x) + 1 == 5 ? 0 : (x) + 1)

#if __has_builtin(__builtin_amdgcn_exp2f)
#define EXP2(x) __builtin_amdgcn_exp2f(x)
#else
#define EXP2(x) exp2f(x)
#endif
#define MAX3(a, b, c) fmaxf(fmaxf((a), (b)), (c))

static __device__ __forceinline__ void glds16(const void* g, void* l) {
  __builtin_amdgcn_global_load_lds(
      (__attribute__((address_space(1))) void*)(g),
      (__attribute__((address_space(3))) void*)(l), 16, 0, 0);
}
#define SBAR() do { asm volatile("" ::: "memory"); __builtin_amdgcn_s_barrier(); asm volatile("" ::: "memory"); } while (0)

// ---------------- pre-pass: fp32 K,V -> fp16 LDS-image layout in ws ----------------
__global__ __launch_bounds__(256)
void cvt_pack(const float* __restrict__ Kg, const float* __restrict__ Vg,
              _Float16* __restrict__ Kw, _Float16* __restrict__ Vw) {
  const int id = (int)(blockIdx.x * 256 + threadIdx.x);
  const int tensor = id >> 19;
  const int cid = id & 0x7FFFF;
  const int bht = cid >> 9;       // bh*NT + t
  const int bh = bht >> 5, t = bht & 31;
  const int loc = cid & 511;
  const int a = loc >> 3;
  const int s = loc & 7;
  size_t srcoff;
  if (tensor == 0) {
    const int r = a;
    srcoff = (size_t)bh * (S_LEN * D_DIM) + (size_t)(t * 64 + r) * D_DIM + 8 * (s ^ (r & 7));
  } else {
    const int TI = a, c2 = s;
    const int it = TI & 3;
    const int vgi = ((TI >> 3) & 3) | (((TI >> 2) & 1) << 2) | (((TI >> 5) & 1) << 3);
    const int kq = c2 >> 1, d8 = (c2 & 1) * 8;
    srcoff = (size_t)bh * (S_LEN * D_DIM) + (size_t)(t * 64 + 4 * vgi + kq) * D_DIM + it * 16 + d8;
  }
  const float* src = (tensor ? Vg : Kg) + srcoff;
  float4v x = *(const float4v*)src;
  float4v y = *(const float4v*)(src + 4);
  half8 h = { (_Float16)x[0], (_Float16)x[1], (_Float16)x[2], (_Float16)x[3],
              (_Float16)y[0], (_Float16)y[1], (_Float16)y[2], (_Float16)y[3] };
  _Float16* dst = (tensor ? Vw : Kw) + (size_t)bht * 4096 + (size_t)loc * 8;
  *(half8*)dst = h;
}

// ---- per-group online softmax + fp16 pack (deferred cross-lane max) ----
static __device__ __forceinline__ void softmax_pack(f32x4 (&s)[4], float& m_run,
                                                    f32x4& l_acc, f32x4 (&o)[4],
                                                    half8 (&pb)[2]) {
  float plm;
  {
    float a0 = MAX3(s[0][0], s[0][1], s[0][2]);
    float a1 = MAX3(s[0][3], s[1][0], s[1][1]);
    float a2 = MAX3(s[1][2], s[1][3], s[2][0]);
    float a3 = MAX3(s[2][1], s[2][2], s[2][3]);
    float a4 = MAX3(s[3][0], s[3][1], s[3][2]);
    plm = fmaxf(MAX3(a0, a1, a2), MAX3(a3, a4, s[3][3]));
  }
  float p[16];
  if (__any(plm > m_run + 8.f)) {   // rare: true rescale path
    float pmax = fmaxf(plm, __shfl_xor(plm, 16, 64));
    pmax = fmaxf(pmax, __shfl_xor(pmax, 32, 64));
    const float mnew  = fmaxf(m_run, pmax);
    const float alpha = EXP2(m_run - mnew);
    m_run = mnew;
#pragma unroll
    for (int i = 0; i < 16; ++i)
      p[i] = EXP2(s[i >> 2][i & 3] - mnew);
    l_acc[0] *= alpha;
#pragma unroll
    for (int dt = 0; dt < 4; ++dt) {
      o[dt][0] *= alpha; o[dt][1] *= alpha;
      o[dt][2] *= alpha; o[dt][3] *= alpha;
    }
  } else {                          // common: no rescale, no cross-lane reduce
#pragma unroll
    for (int i = 0; i < 16; ++i)
      p[i] = EXP2(s[i >> 2][i & 3] - m_run);
  }
#pragma unroll
  for (int kc = 0; kc < 2; ++kc) {
    fp16x2 x0 = __builtin_amdgcn_cvt_pkrtz(p[8 * kc + 0], p[8 * kc + 1]);
    fp16x2 x1 = __builtin_amdgcn_cvt_pkrtz(p[8 * kc + 2], p[8 * kc + 3]);
    fp16x2 x2 = __builtin_amdgcn_cvt_pkrtz(p[8 * kc + 4], p[8 * kc + 5]);
    fp16x2 x3 = __builtin_amdgcn_cvt_pkrtz(p[8 * kc + 6], p[8 * kc + 7]);
    half8 pk = { (_Float16)x0[0], (_Float16)x0[1], (_Float16)x1[0], (_Float16)x1[1],
                 (_Float16)x2[0], (_Float16)x2[1], (_Float16)x3[0], (_Float16)x3[1] };
    pb[kc] = pk;
  }
}

// ---------------- main: QBLK=128, 4 waves, 5-slot ring, T15 pipeline,
// ---------------- XCD-swizzled flat grid, early STAGE (round-12 schedule).
// RACE-SAFE by 5-slot distance: per tile T: STAGE(T+2) -> vmcnt(8) -> SBAR_T.
// STAGE(T+2) overwrites slot (T+2)%5, holding tile T-3. A wave issuing this
// has completed ITER(T-1); every other wave has passed SBAR_{T-1}, hence
// completed ITER(T-2), whose lgkmcnt(15) drained TRRD(T-3); QK(T-3) ds_reads
// were consumed in ITER(T-3). So all reads of tile T-3 are complete
// device-wide before the overwrite can land.
__global__ __launch_bounds__(256, 2)
void fa_fwd2(const float* __restrict__ Qg, const _Float16* __restrict__ Kw,
             const _Float16* __restrict__ Vw, float* __restrict__ Og) {
  __shared__ __attribute__((aligned(128))) _Float16 Klds[5][4096];
  __shared__ __attribute__((aligned(128))) _Float16 Vlds[5][4096];

  const int tid  = (int)threadIdx.x;
  const int wid  = tid >> 6;
  const int lane = tid & 63;
  const int g    = lane >> 4;
  const int c    = lane & 15;

  // XCD swizzle: all 16 q-tiles of one bh share the same XCD L2 (m09 round-robin).
  const int f     = (int)blockIdx.x;
  const int bh    = (f & 7) * 4 + (f >> 7);
  const int qtile = (f >> 3) & 15;
  const size_t base = (size_t)bh * (S_LEN * D_DIM);

  const int qrowA = qtile * QBLK + wid * 16 + c;
  const int qrowB = qrowA + 64;
  half8 qfA[2], qfB[2];
#pragma unroll
  for (int kt = 0; kt < 2; ++kt) {
    const float* qpA = Qg + base + (size_t)qrowA * D_DIM + kt * 32 + 8 * g;
    const float* qpB = Qg + base + (size_t)qrowB * D_DIM + kt * 32 + 8 * g;
    float4v a0 = *(const float4v*)qpA;
    float4v a1 = *(const float4v*)(qpA + 4);
    float4v b0 = *(const float4v*)qpB;
    float4v b1 = *(const float4v*)(qpB + 4);
    half8 qa = { (_Float16)(a0[0] * QSCALE), (_Float16)(a0[1] * QSCALE),
                 (_Float16)(a0[2] * QSCALE), (_Float16)(a0[3] * QSCALE),
                 (_Float16)(a1[0] * QSCALE), (_Float16)(a1[1] * QSCALE),
                 (_Float16)(a1[2] * QSCALE), (_Float16)(a1[3] * QSCALE) };
    half8 qb = { (_Float16)(b0[0] * QSCALE), (_Float16)(b0[1] * QSCALE),
                 (_Float16)(b0[2] * QSCALE), (_Float16)(b0[3] * QSCALE),
                 (_Float16)(b1[0] * QSCALE), (_Float16)(b1[1] * QSCALE),
                 (_Float16)(b1[2] * QSCALE), (_Float16)(b1[3] * QSCALE) };
    qfA[kt] = qa; qfB[kt] = qb;
  }

  const f32x4 zero4 = {0.f, 0.f, 0.f, 0.f};
  f32x4 o_accA[4], o_accB[4];
#pragma unroll
  for (int i = 0; i < 4; ++i) { o_accA[i] = zero4; o_accB[i] = zero4; }
  f32x4 l_accA = zero4, l_accB = zero4;
  const half8 ones8 = { (_Float16)1.f, (_Float16)1.f, (_Float16)1.f, (_Float16)1.f,
                        (_Float16)1.f, (_Float16)1.f, (_Float16)1.f, (_Float16)1.f };
  float m_runA = -1.0e30f, m_runB = -1.0e30f;

  const char* kbase = (const char*)Kw + ((size_t)(bh * NT) << 13);
  const char* vbase = (const char*)Vw + ((size_t)(bh * NT) << 13);
  const int woff = wid * 2048 + lane * 16;

#define STAGE(b, t) do { \
    const char* ks_ = kbase + ((size_t)(t) << 13) + woff; \
    const char* vs_ = vbase + ((size_t)(t) << 13) + woff; \
    glds16(ks_,        &Klds[(b)][wid * 1024]); \
    glds16(ks_ + 1024, &Klds[(b)][wid * 1024 + 512]); \
    glds16(vs_,        &Vlds[(b)][wid * 1024]); \
    glds16(vs_ + 1024, &Vlds[(b)][wid * 1024 + 512]); \
  } while (0)

  const uint32_t vtb0 = (uint32_t)(uintptr_t)(&Vlds[0][0]) + 1024u * (uint32_t)g + 8u * (uint32_t)c;

  // pipeline register state: two sets (prev/cur alternate by tile parity)
  half4 vr0[16], vr1[16];
  half8 pbA0[2], pbB0[2], pbA1[2], pbB1[2];

#define TRRD_SET(VR, vt) do { \
    asm volatile("ds_read_b64_tr_b16 %0, %1 offset:0"    : "=v"(VR[0])  : "v"(vt)); \
    asm volatile("ds_read_b64_tr_b16 %0, %1 offset:128"  : "=v"(VR[1])  : "v"(vt)); \
    asm volatile("ds_read_b64_tr_b16 %0, %1 offset:256"  : "=v"(VR[2])  : "v"(vt)); \
    asm volatile("ds_read_b64_tr_b16 %0, %1 offset:384"  : "=v"(VR[3])  : "v"(vt)); \
    asm volatile("ds_read_b64_tr_b16 %0, %1 offset:512"  : "=v"(VR[4])  : "v"(vt)); \
    asm volatile("ds_read_b64_tr_b16 %0, %1 offset:640"  : "=v"(VR[5])  : "v"(vt)); \
    asm volatile("ds_read_b64_tr_b16 %0, %1 offset:768"  : "=v"(VR[6])  : "v"(vt)); \
    asm volatile("ds_read_b64_tr_b16 %0, %1 offset:896"  : "=v"(VR[7])  : "v"(vt)); \
    asm volatile("ds_read_b64_tr_b16 %0, %1 offset:4096" : "=v"(VR[8])  : "v"(vt)); \
    asm volatile("ds_read_b64_tr_b16 %0, %1 offset:4224" : "=v"(VR[9])  : "v"(vt)); \
    asm volatile("ds_read_b64_tr_b16 %0, %1 offset:4352" : "=v"(VR[10]) : "v"(vt)); \
    asm volatile("ds_read_b64_tr_b16 %0, %1 offset:4480" : "=v"(VR[11]) : "v"(vt)); \
    asm volatile("ds_read_b64_tr_b16 %0, %1 offset:4608" : "=v"(VR[12]) : "v"(vt)); \
    asm volatile("ds_read_b64_tr_b16 %0, %1 offset:4736" : "=v"(VR[13]) : "v"(vt)); \
    asm volatile("ds_read_b64_tr_b16 %0, %1 offset:4864" : "=v"(VR[14]) : "v"(vt)); \
    asm volatile("ds_read_b64_tr_b16 %0, %1 offset:4992" : "=v"(VR[15]) : "v"(vt)); \
  } while (0)

#define PV_BLOCK(VR, PBA, PBB) do { \
    __builtin_amdgcn_s_setprio(1); \
    _Pragma("unroll") \
    for (int kc = 0; kc < 2; ++kc) { \
      _Pragma("unroll") \
      for (int dt = 0; dt < 4; ++dt) { \
        half8 vf = __builtin_shufflevector(VR[kc * 8 + dt], VR[kc * 8 + 4 + dt], \
                                           0, 1, 2, 3, 4, 5, 6, 7); \
        o_accA[dt] = __builtin_amdgcn_mfma_f32_16x16x32_f16(vf, PBA[kc], o_accA[dt], 0, 0, 0); \
        o_accB[dt] = __builtin_amdgcn_mfma_f32_16x16x32_f16(vf, PBB[kc], o_accB[dt], 0, 0, 0); \
      } \
      l_accA = __builtin_amdgcn_mfma_f32_16x16x32_f16(ones8, PBA[kc], l_accA, 0, 0, 0); \
      l_accB = __builtin_amdgcn_mfma_f32_16x16x32_f16(ones8, PBB[kc], l_accB, 0, 0, 0); \
    } \
    __builtin_amdgcn_s_setprio(0); \
  } while (0)

  // ITER(T, SL): SL = T%5 (uniform). STAGE(T+2) -> vmcnt(8) -> SBAR -> QK(T)
  // -> TRRD(T) -> [PV(T-1)] -> softmax(T)
#define ITER(T, SL, VRC, PBAC, PBBC, DO_PV, VRP, PBAP, PBBP) do { \
    if ((T) + 2 < NT) { \
      STAGE(NEXT5(NEXT5(SL)), (T) + 2); \
      asm volatile("s_waitcnt vmcnt(8)" ::: "memory"); \
    } else if ((T) + 1 < NT) { \
      asm volatile("s_waitcnt vmcnt(4)" ::: "memory"); \
    } else { \
      asm volatile("s_waitcnt vmcnt(0)" ::: "memory"); \
    } \
    __builtin_amdgcn_sched_barrier(0); \
    SBAR(); \
    const _Float16* kcur = &Klds[(SL)][0]; \
    const uint32_t vt = vtb0 + (uint32_t)((SL) << 13); \
    f32x4 sA[4], sB[4]; \
    _Pragma("unroll") \
    for (int ct = 0; ct < 4; ++ct) { sA[ct] = zero4; sB[ct] = zero4; } \
    __builtin_amdgcn_s_setprio(1); \
    _Pragma("unroll") \
    for (int ct = 0; ct < 4; ++ct) { \
      _Pragma("unroll") \
      for (int kt = 0; kt < 2; ++kt) { \
        half8 kb = *(half8*)&kcur[(ct * 16 + c) * 64 + (((4 * kt + g) ^ (c & 7)) << 3)]; \
        sA[ct] = __builtin_amdgcn_mfma_f32_16x16x32_f16(kb, qfA[kt], sA[ct], 0, 0, 0); \
        sB[ct] = __builtin_amdgcn_mfma_f32_16x16x32_f16(kb, qfB[kt], sB[ct], 0, 0, 0); \
      } \
    } \
    __builtin_amdgcn_s_setprio(0); \
    TRRD_SET(VRC, vt); \
    if (DO_PV) { \
      asm volatile("s_waitcnt lgkmcnt(15)" ::: "memory"); /* drains prev's 16 tr-reads */ \
      __builtin_amdgcn_sched_barrier(0); \
      PV_BLOCK(VRP, PBAP, PBBP); \
    } \
    softmax_pack(sA, m_runA, l_accA, o_accA, PBAC); \
    softmax_pack(sB, m_runB, l_accB, o_accB, PBBC); \
  } while (0)

  // drain Q loads so vmcnt arithmetic counts only STAGE loads
  asm volatile("s_waitcnt vmcnt(0)" ::: "memory");
  STAGE(0, 0);
  STAGE(1, 1);

  ITER(0, 0, vr0, pbA0, pbB0, 0, vr1, pbA1, pbB1);
  int sl = 1;   // slot of tile t at loop top (uniform, SGPR)
  for (int t = 1; t + 1 < NT; t += 2) {
    ITER(t, sl, vr1, pbA1, pbB1, 1, vr0, pbA0, pbB0);
    const int sl2 = NEXT5(sl);
    ITER(t + 1, sl2, vr0, pbA0, pbB0, 1, vr1, pbA1, pbB1);
    sl = NEXT5(sl2);
  }
  ITER(NT - 1, sl, vr1, pbA1, pbB1, 1, vr0, pbA0, pbB0);
  // drain final tile's tr-reads, then last PV
  asm volatile("s_waitcnt lgkmcnt(0)" ::: "memory");
  __builtin_amdgcn_sched_barrier(0);
  PV_BLOCK(vr1, pbA1, pbB1);
#undef ITER
#undef PV_BLOCK
#undef TRRD_SET
#undef STAGE

  const float invA = 1.0f / l_accA[0];
  const float invB = 1.0f / l_accB[0];
#pragma unroll
  for (int dt = 0; dt < 4; ++dt) {
    float4v wA = { o_accA[dt][0] * invA, o_accA[dt][1] * invA,
                   o_accA[dt][2] * invA, o_accA[dt][3] * invA };
    *(float4v*)&Og[base + (size_t)qrowA * D_DIM + dt * 16 + g * 4] = wA;
    float4v wB = { o_accB[dt][0] * invB, o_accB[dt][1] * invB,
                   o_accB[dt][2] * invB, o_accB[dt][3] * invB };
    *(float4v*)&Og[base + (size_t)qrowB * D_DIM + dt * 16 + g * 4] = wB;
  }
}

// ---------------- fallback (round-5 kernel) if ws too small ----------------
__global__ __launch_bounds__(256)
void fa_fwd_fb(const float* __restrict__ Qg, const float* __restrict__ Kg,
               const float* __restrict__ Vg, float* __restrict__ Og) {
  __shared__ _Float16 Klds[KVBLK * KSTR];
  __shared__ __attribute__((aligned(128))) _Float16 Vlds[KVBLK * D_DIM];

  const int tid  = (int)threadIdx.x;
  const int wid  = tid >> 6;
  const int lane = tid & 63;
  const int g    = lane >> 4;
  const int c    = lane & 15;

  const int qtile = (int)blockIdx.x;
  const int bh    = (int)blockIdx.y;
  const size_t base = (size_t)bh * (S_LEN * D_DIM);

  const int qrow = qtile * 64 + wid * 16 + c;
  half8 qf[2];
#pragma unroll
  for (int kt = 0; kt < 2; ++kt) {
    const float* qp = Qg + base + (size_t)qrow * D_DIM + kt * 32 + 8 * g;
    float4v a = *(const float4v*)qp;
    float4v b = *(const float4v*)(qp + 4);
    half8 q;
    q[0] = (_Float16)(a[0] * QSCALE); q[1] = (_Float16)(a[1] * QSCALE);
    q[2] = (_Float16)(a[2] * QSCALE); q[3] = (_Float16)(a[3] * QSCALE);
    q[4] = (_Float16)(b[0] * QSCALE); q[5] = (_Float16)(b[1] * QSCALE);
    q[6] = (_Float16)(b[2] * QSCALE); q[7] = (_Float16)(b[3] * QSCALE);
    qf[kt] = q;
  }

  const f32x4 zero4 = {0.f, 0.f, 0.f, 0.f};
  f32x4 o_acc[4];
#pragma unroll
  for (int i = 0; i < 4; ++i) o_acc[i] = zero4;
  float m_run = -1.0e30f, l_run = 0.f;

  const int srow = tid >> 4;
  const int scol = (tid & 15) * 4;
  const int vgi = tid >> 4;
  const int vlg = tid & 15;
  const int vk  = vgi * 4 + (vlg >> 2);
  const int vsub = 8 * (vgi & 3) + 4 * ((vgi >> 2) & 1) + 32 * (vgi >> 3);
  const uint32_t vtb = (uint32_t)(uintptr_t)(&Vlds[0]) + 1024u * (uint32_t)g + 8u * (uint32_t)c;

  for (int t = 0; t < NT; ++t) {
    const int kv0 = t * KVBLK;
    __syncthreads();
#pragma unroll
    for (int rr = 0; rr < 4; ++rr) {
      const int row = srow + rr * 16;
      const float* kp = Kg + base + (size_t)(kv0 + row) * D_DIM + scol;
      float4v kx = *(const float4v*)kp;
      half4 kh = { (_Float16)kx[0], (_Float16)kx[1], (_Float16)kx[2], (_Float16)kx[3] };
      *(half4*)&Klds[row * KSTR + scol] = kh;
    }
#pragma unroll
    for (int it = 0; it < 4; ++it) {
      const int d = it * 16 + (vlg & 3) * 4;
      const float* vp = Vg + base + (size_t)(kv0 + vk) * D_DIM + d;
      float4v vx = *(const float4v*)vp;
      half4 vh = { (_Float16)vx[0], (_Float16)vx[1], (_Float16)vx[2], (_Float16)vx[3] };
      *(half4*)&Vlds[(vsub + it) * 64 + (vlg >> 2) * 16 + (vlg & 3) * 4] = vh;
    }
    __syncthreads();

    f32x4 s_acc[4];
#pragma unroll
    for (int ct = 0; ct < 4; ++ct) s_acc[ct] = zero4;
#pragma unroll
    for (int ct = 0; ct < 4; ++ct) {
#pragma unroll
      for (int kt = 0; kt < 2; ++kt) {
        half8 kb = *(half8*)&Klds[(ct * 16 + c) * KSTR + kt * 32 + 8 * g];
        s_acc[ct] = __builtin_amdgcn_mfma_f32_16x16x32_f16(kb, qf[kt], s_acc[ct], 0, 0, 0);
      }
    }

    float pmax = -1.0e30f;
#pragma unroll
    for (int ct = 0; ct < 4; ++ct)
#pragma unroll
      for (int r = 0; r < 4; ++r) pmax = fmaxf(pmax, s_acc[ct][r]);
    pmax = fmaxf(pmax, __shfl_xor(pmax, 16, 64));
    pmax = fmaxf(pmax, __shfl_xor(pmax, 32, 64));
    const float mnew  = fmaxf(m_run, pmax);
    const float alpha = exp2f(m_run - mnew);
    m_run = mnew;

    float p[16];
    float psum = 0.f;
#pragma unroll
    for (int i = 0; i < 16; ++i) {
      p[i] = exp2f(s_acc[i >> 2][i & 3] - mnew);
      psum += p[i];
    }
    psum += __shfl_xor(psum, 16, 64);
    psum += __shfl_xor(psum, 32, 64);
    l_run = l_run * alpha + psum;
#pragma unroll
    for (int dt = 0; dt < 4; ++dt) {
      o_acc[dt][0] *= alpha; o_acc[dt][1] *= alpha;
      o_acc[dt][2] *= alpha; o_acc[dt][3] *= alpha;
    }

    half8 pb[2];
#pragma unroll
    for (int kc = 0; kc < 2; ++kc) {
      fp16x2 x0 = __builtin_amdgcn_cvt_pkrtz(p[8 * kc + 0], p[8 * kc + 1]);
      fp16x2 x1 = __builtin_amdgcn_cvt_pkrtz(p[8 * kc + 2], p[8 * kc + 3]);
      fp16x2 x2 = __builtin_amdgcn_cvt_pkrtz(p[8 * kc + 4], p[8 * kc + 5]);
      fp16x2 x3 = __builtin_amdgcn_cvt_pkrtz(p[8 * kc + 6], p[8 * kc + 7]);
      half8 pk = { (_Float16)x0[0], (_Float16)x0[1], (_Float16)x1[0], (_Float16)x1[1],
                   (_Float16)x2[0], (_Float16)x2[1], (_Float16)x3[0], (_Float16)x3[1] };
      pb[kc] = pk;
    }

    half4 vr[16];
#define TRRD(i, offstr) \
    asm volatile("ds_read_b64_tr_b16 %0, %1 offset:" offstr : "=v"(vr[i]) : "v"(vtb))
    TRRD(0,  "0");    TRRD(1,  "128");  TRRD(2,  "256");  TRRD(3,  "384");
    TRRD(4,  "512");  TRRD(5,  "640");  TRRD(6,  "768");  TRRD(7,  "896");
    TRRD(8,  "4096"); TRRD(9,  "4224"); TRRD(10, "4352"); TRRD(11, "4480");
    TRRD(12, "4608"); TRRD(13, "4736"); TRRD(14, "4864"); TRRD(15, "4992");
#undef TRRD
    asm volatile("s_waitcnt lgkmcnt(0)" ::: "memory");
    __builtin_amdgcn_sched_barrier(0);

#pragma unroll
    for (int kc = 0; kc < 2; ++kc) {
#pragma unroll
      for (int dt = 0; dt < 4; ++dt) {
        half8 vf = __builtin_shufflevector(vr[kc * 8 + dt], vr[kc * 8 + 4 + dt],
                                           0, 1, 2, 3, 4, 5, 6, 7);
        o_acc[dt] = __builtin_amdgcn_mfma_f32_16x16x32_f16(vf, pb[kc], o_acc[dt], 0, 0, 0);
      }
    }
  }

  const float invl = 1.0f / l_run;
#pragma unroll
  for (int dt = 0; dt < 4; ++dt) {
    float4v w = { o_acc[dt][0] * invl, o_acc[dt][1] * invl,
                  o_acc[dt][2] * invl, o_acc[dt][3] * invl };
    *(float4v*)&Og[base + (size_t)qrow * D_DIM + dt * 16 + g * 4] = w;
  }
}

extern "C" void kernel_launch(void* const* d_in, const int* in_sizes, int n_in,
                              void* d_out, int out_size, void* d_ws, size_t ws_size,
                              hipStream_t stream) {
  const float* Q = (const float*)d_in[0];
  const float* K = (const float*)d_in[1];
  const float* V = (const float*)d_in[2];
  float* O = (float*)d_out;
  if (ws_size >= (size_t)16 * 1024 * 1024) {
    _Float16* Kw = (_Float16*)d_ws;
    _Float16* Vw = Kw + (size_t)NBH * S_LEN * D_DIM;
    hipLaunchKernelGGL(cvt_pack, dim3(4096), dim3(256), 0, stream, K, V, Kw, Vw);
    hipLaunchKernelGGL(fa_fwd2, dim3((S_LEN / QBLK) * NBH), dim3(256), 0, stream, Q, Kw, Vw, O);
  } else {
    hipLaunchKernelGGL(fa_fwd_fb, dim3(S_LEN / 64, NBH), dim3(256), 0, stream, Q, K, V, O);
  }
}